// Round 7
// baseline (3304.201 us; speedup 1.0000x reference)
//
#include <hip/hip_runtime.h>

#define NB 8
#define NPTS 8192
#define NC_FEAT 64
#define NS 2048
#define NK 32

typedef float v2f __attribute__((ext_vector_type(2)));

// Exact reference arithmetic for squared distance: no fma contraction,
// sum association ((dx^2 + dy^2) + dz^2) to match XLA's linear reduce.
__device__ __forceinline__ float d2_ref(float px, float py, float pz,
                                        float qx, float qy, float qz) {
  float dx = __fsub_rn(px, qx);
  float dy = __fsub_rn(py, qy);
  float dz = __fsub_rn(pz, qz);
  return __fadd_rn(__fadd_rn(__fmul_rn(dx, dx), __fmul_rn(dy, dy)),
                   __fmul_rn(dz, dz));
}

// DPP max-combine on packed u64 key. bound_ctrl=true -> OOB lanes give 0.
#define DPP_KEYMAX(key, ctrl)                                                 \
  {                                                                           \
    unsigned _lo = (unsigned)__builtin_amdgcn_update_dpp(                     \
        0, (int)(unsigned)(key), (ctrl), 0xf, 0xf, true);                     \
    unsigned _hi = (unsigned)__builtin_amdgcn_update_dpp(                     \
        0, (int)(unsigned)((key) >> 32), (ctrl), 0xf, 0xf, true);             \
    unsigned long long _o = ((unsigned long long)_hi << 32) | _lo;            \
    if (_o > (key)) (key) = _o;                                               \
  }

// DPP float min/max combine; bound_ctrl=false keeps `old`(=v) for OOB lanes
// (identity for min/max).
#define DPP_FMIN(v, ctrl)                                                     \
  {                                                                           \
    float _o = __int_as_float(__builtin_amdgcn_update_dpp(                    \
        __float_as_int(v), __float_as_int(v), (ctrl), 0xf, 0xf, false));      \
    (v) = fminf((v), _o);                                                     \
  }
#define DPP_FMAX(v, ctrl)                                                     \
  {                                                                           \
    float _o = __int_as_float(__builtin_amdgcn_update_dpp(                    \
        __float_as_int(v), __float_as_int(v), (ctrl), 0xf, 0xf, false));      \
    (v) = fmaxf((v), _o);                                                     \
  }
#define DPP_RED6_FMIN(v) \
  DPP_FMIN(v, 0x111); DPP_FMIN(v, 0x112); DPP_FMIN(v, 0x114); \
  DPP_FMIN(v, 0x118); DPP_FMIN(v, 0x142); DPP_FMIN(v, 0x143)
#define DPP_RED6_FMAX(v) \
  DPP_FMAX(v, 0x111); DPP_FMAX(v, 0x112); DPP_FMAX(v, 0x114); \
  DPP_FMAX(v, 0x118); DPP_FMAX(v, 0x142); DPP_FMAX(v, 0x143)

__device__ __forceinline__ unsigned msp(unsigned x) {  // spread 10 bits
  x &= 0x3FF;
  x = (x | (x << 16)) & 0x030000FF;
  x = (x | (x << 8)) & 0x0300F00F;
  x = (x | (x << 4)) & 0x030C30C3;
  x = (x | (x << 2)) & 0x09249249;
  return x;
}

// ---------------------------------------------------------------------------
// Kernel 0: FPS with exact per-lane spatial pruning.
// One 512-thread block per batch. Points Morton-sorted (in LDS) so each
// lane's 16 points are spatially compact; a lane skips its 16-point distance
// update when a conservative triangle-inequality bound proves no dist can
// change (bit-exact: min(dist,d)=dist whenever d>=dist). Argmax keys are
// (dist | ~orig_idx | sorted_idx): tie-break on ORIGINAL index (exact
// jnp.argmax semantics, permutation-invariant); sorted idx rides along to
// locate coords. Reduce machinery identical to the proven round-5 kernel.
// ---------------------------------------------------------------------------
__global__ __launch_bounds__(512)
void k_fps(const float* __restrict__ pos, float* __restrict__ new_xyz) {
#pragma clang fp contract(off)
  // LDS: sx/sy/sz[8192] (sx aliased by morton keys K during sort),
  //      P[8192] perm payload, then rk[2][16] u64, wavebb[8][6], bbx[6], last0
  __shared__ __align__(16) float smem[4 * NPTS + 128];
  float* sx = smem;
  float* sy = smem + NPTS;
  float* sz = smem + 2 * NPTS;
  unsigned* K = (unsigned*)smem;  // alias sx (dead before sx is written)
  unsigned* P = (unsigned*)(smem + 3 * NPTS);
  unsigned long long* rk = (unsigned long long*)(smem + 4 * NPTS);  // 64 f
  float* wavebb = smem + 4 * NPTS + 64;                             // 48 f
  float* bbx = smem + 4 * NPTS + 64 + 48;                           // 6 f
  int* last0p = (int*)(smem + 4 * NPTS + 64 + 48 + 6);

  const int tid = threadIdx.x;
  const int b = blockIdx.x;
  const int lane = tid & 63;
  const int wave = tid >> 6;
  const float* p = pos + (size_t)b * NPTS * 3;

  // ---- phase 1a: batch bbox (block reduce) ----
  float mnx = 3e38f, mny = 3e38f, mnz = 3e38f;
  float mxx = -3e38f, mxy = -3e38f, mxz = -3e38f;
  for (int i = tid; i < NPTS; i += 512) {
    float x = p[3 * i], y = p[3 * i + 1], z = p[3 * i + 2];
    mnx = fminf(mnx, x); mxx = fmaxf(mxx, x);
    mny = fminf(mny, y); mxy = fmaxf(mxy, y);
    mnz = fminf(mnz, z); mxz = fmaxf(mxz, z);
  }
  DPP_RED6_FMIN(mnx); DPP_RED6_FMIN(mny); DPP_RED6_FMIN(mnz);
  DPP_RED6_FMAX(mxx); DPP_RED6_FMAX(mxy); DPP_RED6_FMAX(mxz);
  if (lane == 63) {
    wavebb[wave * 6 + 0] = mnx; wavebb[wave * 6 + 1] = mny;
    wavebb[wave * 6 + 2] = mnz; wavebb[wave * 6 + 3] = mxx;
    wavebb[wave * 6 + 4] = mxy; wavebb[wave * 6 + 5] = mxz;
  }
  __syncthreads();
  if (tid == 0) {
    float a0 = 3e38f, a1 = 3e38f, a2 = 3e38f;
    float a3 = -3e38f, a4 = -3e38f, a5 = -3e38f;
    for (int w = 0; w < 8; ++w) {
      a0 = fminf(a0, wavebb[w * 6 + 0]); a1 = fminf(a1, wavebb[w * 6 + 1]);
      a2 = fminf(a2, wavebb[w * 6 + 2]); a3 = fmaxf(a3, wavebb[w * 6 + 3]);
      a4 = fmaxf(a4, wavebb[w * 6 + 4]); a5 = fmaxf(a5, wavebb[w * 6 + 5]);
    }
    bbx[0] = a0; bbx[1] = a1; bbx[2] = a2;
    bbx[3] = 1023.0f / fmaxf(a3 - a0, 1e-30f);
    bbx[4] = 1023.0f / fmaxf(a4 - a1, 1e-30f);
    bbx[5] = 1023.0f / fmaxf(a5 - a2, 1e-30f);
  }
  __syncthreads();
  const float ox = bbx[0], oy = bbx[1], oz = bbx[2];
  const float gx = bbx[3], gy = bbx[4], gz = bbx[5];

  // ---- phase 1b: morton codes ----
  for (int i = tid; i < NPTS; i += 512) {
    float x = p[3 * i], y = p[3 * i + 1], z = p[3 * i + 2];
    unsigned ux = (unsigned)fminf(fmaxf((x - ox) * gx, 0.0f), 1023.0f);
    unsigned uy = (unsigned)fminf(fmaxf((y - oy) * gy, 0.0f), 1023.0f);
    unsigned uz = (unsigned)fminf(fmaxf((z - oz) * gz, 0.0f), 1023.0f);
    K[i] = msp(ux) | (msp(uy) << 1) | (msp(uz) << 2);
    P[i] = (unsigned)i;
  }

  // ---- phase 2: bitonic sort (K asc, payload P). Any valid permutation is
  // correct; sort only provides spatial locality. ----
  for (int k2 = 2; k2 <= NPTS; k2 <<= 1) {
    for (int j = k2 >> 1; j > 0; j >>= 1) {
      __syncthreads();
      for (int t = 0; t < 16; ++t) {
        int i = t * 512 + tid;
        int ixj = i ^ j;
        if (ixj > i) {
          unsigned a = K[i], c = K[ixj];
          bool up = ((i & k2) == 0);
          if ((a > c) == up) {
            K[i] = c; K[ixj] = a;
            unsigned pa = P[i]; P[i] = P[ixj]; P[ixj] = pa;
          }
        }
      }
    }
  }
  __syncthreads();

  // ---- phase 3: gather coords into sorted order (overwrites K alias) ----
  for (int i = tid; i < NPTS; i += 512) {
    unsigned u = P[i];
    if (u == 0) *last0p = i;
    sx[i] = p[3 * u];
    sy[i] = p[3 * u + 1];
    sz[i] = p[3 * u + 2];
  }
  if (tid < 32) rk[tid] = 0ull;
  __syncthreads();

  // ---- phase 4: per-lane init: 16 sorted pts, orig idx, bbox bound ----
  const int base = tid * 16;
  v2f px[8], py[8], pz[8], di[8];
  unsigned opk[8];
#pragma unroll
  for (int k = 0; k < 8; ++k) {
    px[k] = (v2f){sx[base + 2 * k], sx[base + 2 * k + 1]};
    py[k] = (v2f){sy[base + 2 * k], sy[base + 2 * k + 1]};
    pz[k] = (v2f){sz[base + 2 * k], sz[base + 2 * k + 1]};
    di[k] = (v2f){1e10f, 1e10f};
    opk[k] = (P[base + 2 * k] & 0xFFFF) | (P[base + 2 * k + 1] << 16);
  }
  float lmnx = 3e38f, lmny = 3e38f, lmnz = 3e38f;
  float lmxx = -3e38f, lmxy = -3e38f, lmxz = -3e38f;
#pragma unroll
  for (int k = 0; k < 8; ++k) {
    lmnx = fminf(lmnx, fminf(px[k].x, px[k].y));
    lmxx = fmaxf(lmxx, fmaxf(px[k].x, px[k].y));
    lmny = fminf(lmny, fminf(py[k].x, py[k].y));
    lmxy = fmaxf(lmxy, fmaxf(py[k].x, py[k].y));
    lmnz = fminf(lmnz, fminf(pz[k].x, pz[k].y));
    lmxz = fmaxf(lmxz, fmaxf(pz[k].x, pz[k].y));
  }
  const float cx = (lmnx + lmxx) * 0.5f;
  const float cy = (lmny + lmxy) * 0.5f;
  const float cz = (lmnz + lmxz) * 0.5f;
  float r2m = 0.0f;
#pragma unroll
  for (int k = 0; k < 8; ++k) {
    r2m = fmaxf(r2m, d2_ref(px[k].x, py[k].x, pz[k].x, cx, cy, cz));
    r2m = fmaxf(r2m, d2_ref(px[k].y, py[k].y, pz[k].y, cx, cy, cz));
  }
  const float r = sqrtf(r2m) * 1.001f;  // conservative inflation
  float T = 3.4e38f;                    // first iteration: everyone active
  unsigned long long key = 0;

  int last = *last0p;
  if (tid == 0) {
    new_xyz[((size_t)b * NS) * 3 + 0] = sx[last];
    new_xyz[((size_t)b * NS) * 3 + 1] = sy[last];
    new_xyz[((size_t)b * NS) * 3 + 2] = sz[last];
  }
  int buf = 0;

  for (int it = 1; it < NS; ++it) {
    float qx = sx[last], qy = sy[last], qz = sz[last];
    float ddx = cx - qx, ddy = cy - qy, ddz = cz - qz;
    float dc2 = ddx * ddx + ddy * ddy + ddz * ddz;
    if (dc2 <= T) {
      // update dists (exact reference arithmetic via contract(off))
#pragma unroll
      for (int k = 0; k < 8; ++k) {
        v2f dx = px[k] - qx;
        v2f dy = py[k] - qy;
        v2f dz = pz[k] - qz;
        v2f d2 = (dx * dx + dy * dy) + dz * dz;
        di[k] = __builtin_elementwise_min(di[k], d2);
      }
      v2f m0 = __builtin_elementwise_max(di[0], di[1]);
      v2f m1 = __builtin_elementwise_max(di[2], di[3]);
      v2f m2 = __builtin_elementwise_max(di[4], di[5]);
      v2f m3 = __builtin_elementwise_max(di[6], di[7]);
      v2f m4 = __builtin_elementwise_max(m0, m1);
      v2f m5 = __builtin_elementwise_max(m2, m3);
      v2f m6 = __builtin_elementwise_max(m4, m5);
      float bd = fmaxf(m6.x, m6.y);
      int bj = 0;
      unsigned oj = 0;
#pragma unroll
      for (int j = 15; j >= 0; --j) {  // descending: final = lowest j
        float v = (j & 1) ? di[j >> 1].y : di[j >> 1].x;
        unsigned o = (j & 1) ? (opk[j >> 1] >> 16) : (opk[j >> 1] & 0xFFFF);
        if (v == bd) { bj = j; oj = o; }
      }
      // key: [63:32]=dist bits, [25:13]=~orig_idx (tie-break), [12:0]=sorted
      key = ((unsigned long long)__float_as_uint(bd) << 32) |
            ((unsigned long long)((~oj) & 0x1FFFu) << 13) |
            (unsigned)(base + bj);
      float t1 = sqrtf(bd) * 1.001f + r;
      T = t1 * t1 * 1.002f;  // skip only when provably no dist changes
    }
    unsigned long long wk = key;
    DPP_KEYMAX(wk, 0x111);
    DPP_KEYMAX(wk, 0x112);
    DPP_KEYMAX(wk, 0x114);
    DPP_KEYMAX(wk, 0x118);
    DPP_KEYMAX(wk, 0x142);
    DPP_KEYMAX(wk, 0x143);
    if (lane == 63) rk[buf * 16 + wave] = wk;
    __syncthreads();
    wk = rk[buf * 16 + (lane & 15)];
    DPP_KEYMAX(wk, 0x111);
    DPP_KEYMAX(wk, 0x112);
    DPP_KEYMAX(wk, 0x114);
    DPP_KEYMAX(wk, 0x118);
    last = (int)((unsigned)__builtin_amdgcn_readlane((int)(unsigned)wk, 15) &
                 0x1FFFu);
    buf ^= 1;
    if (tid == 0) {
      new_xyz[((size_t)b * NS + it) * 3 + 0] = sx[last];
      new_xyz[((size_t)b * NS + it) * 3 + 1] = sy[last];
      new_xyz[((size_t)b * NS + it) * 3 + 2] = sz[last];
    }
  }
}

// ---------------------------------------------------------------------------
// Kernel 1: blocks 0..1023 = feature transpose (B,C,N)->(B,N,C) 64x64 tiles;
//           block 1024    = weight transpose to [c][o] layout.
// ---------------------------------------------------------------------------
__global__ __launch_bounds__(256)
void k_tp(const float* __restrict__ feat, const float* __restrict__ w0,
          const float* __restrict__ w1, const float* __restrict__ w2,
          float* __restrict__ featT, float* __restrict__ wT) {
  __shared__ float tile[64 * 65];
  const int tid = threadIdx.x;
  if (blockIdx.x < NB * (NPTS / 64)) {
    const int t = blockIdx.x;
    const int b = t >> 7;           // t / 128
    const int n0 = (t & 127) << 6;  // *64
    const int col = tid & 63;
    const int r0 = tid >> 6;  // 0..3
#pragma unroll
    for (int q = 0; q < 16; ++q) {
      int c = r0 + q * 4;
      tile[c * 65 + col] = feat[((size_t)b * NC_FEAT + c) * NPTS + n0 + col];
    }
    __syncthreads();
#pragma unroll
    for (int q = 0; q < 16; ++q) {
      int r = r0 + q * 4;
      featT[((size_t)b * NPTS + n0 + r) * 64 + col] = tile[col * 65 + r];
    }
  } else {
    for (int i = tid; i < 67 * 64; i += 256)
      wT[i] = w0[(i & 63) * 67 + (i >> 6)];
    for (int i = tid; i < 64 * 64; i += 256)
      wT[67 * 64 + i] = w1[(i & 63) * 64 + (i >> 6)];
    for (int i = tid; i < 64 * 128; i += 256)
      wT[67 * 64 + 64 * 64 + i] = w2[(i & 127) * 64 + (i >> 7)];
  }
}

// ---------------------------------------------------------------------------
// Kernel 2: ball query. One wave per query point; first-32-hits via ballot.
// ---------------------------------------------------------------------------
__global__ __launch_bounds__(256)
void k_ball(const float* __restrict__ pos, const float* __restrict__ nxyz,
            int* __restrict__ ballidx) {
  const int wid = (blockIdx.x * 256 + threadIdx.x) >> 6;  // global wave id
  const int lane = threadIdx.x & 63;
  const int b = wid >> 11;
  const float qx = nxyz[wid * 3 + 0];
  const float qy = nxyz[wid * 3 + 1];
  const float qz = nxyz[wid * 3 + 2];
  const float* p = pos + (size_t)b * NPTS * 3;
  int* outp = ballidx + (size_t)wid * NK;

  int cnt = 0;
  int firstidx = 0x7fffffff;
  for (int n0 = 0; n0 < NPTS; n0 += 64) {
    const int i = n0 + lane;
    float d2 = d2_ref(p[3 * i], p[3 * i + 1], p[3 * i + 2], qx, qy, qz);
    bool hit = d2 < 0.25f;
    unsigned long long mask = __ballot(hit);
    int pre = __popcll(mask & ((1ull << lane) - 1ull));
    int slot = cnt + pre;
    if (hit && slot < NK) outp[slot] = i;
    if (hit && slot == 0) firstidx = i;
    cnt += __popcll(mask);
    if (cnt >= NK) break;
  }
#pragma unroll
  for (int m = 32; m >= 1; m >>= 1)
    firstidx = min(firstidx, __shfl_xor(firstidx, m, 64));
  int pad = (firstidx == 0x7fffffff) ? 0 : firstidx;
  int start = cnt < NK ? cnt : NK;
  if (lane < NK && lane >= start) outp[lane] = pad;
}

// ---------------------------------------------------------------------------
// Kernel 3: gather + 3-layer MLP + max over k. One thread per (b,s,k) sample.
// Per-thread column in LDS (stride 256 -> conflict-free), weights read as
// wave-uniform float4 broadcasts from pre-transposed wT.
// ---------------------------------------------------------------------------
#define MLP_FMA16(wr, xc, acc)                                   \
  _Pragma("unroll") for (int o4 = 0; o4 < 16; ++o4) {            \
    float4 w = (wr)[o4];                                         \
    (acc)[o4 * 4 + 0] = fmaf(w.x, (xc), (acc)[o4 * 4 + 0]);      \
    (acc)[o4 * 4 + 1] = fmaf(w.y, (xc), (acc)[o4 * 4 + 1]);      \
    (acc)[o4 * 4 + 2] = fmaf(w.z, (xc), (acc)[o4 * 4 + 2]);      \
    (acc)[o4 * 4 + 3] = fmaf(w.w, (xc), (acc)[o4 * 4 + 3]);      \
  }

__global__ __launch_bounds__(256)
void k_mlp(const float* __restrict__ pos, const float* __restrict__ featT,
           const float* __restrict__ wT, const float* __restrict__ b0,
           const float* __restrict__ b1, const float* __restrict__ b2,
           const int* __restrict__ ballidx, const float* __restrict__ nxyz,
           float* __restrict__ outf) {
  __shared__ float xs[64 * 256];  // 64 KB: per-thread column, stride 256
  const int tid = threadIdx.x;
  const int g = blockIdx.x * 256 + tid;
  const int s = (g >> 5) & (NS - 1);
  const int b = g >> 16;

  const int idx = ballidx[g];
  const float qx = nxyz[((size_t)b * NS + s) * 3 + 0];
  const float qy = nxyz[((size_t)b * NS + s) * 3 + 1];
  const float qz = nxyz[((size_t)b * NS + s) * 3 + 2];
  const float* pp = pos + ((size_t)b * NPTS + idx) * 3;
  const float x0 = __fsub_rn(pp[0], qx);
  const float x1 = __fsub_rn(pp[1], qy);
  const float x2 = __fsub_rn(pp[2], qz);

  const float4* fT = (const float4*)(featT + ((size_t)b * NPTS + idx) * 64);
#pragma unroll
  for (int c4 = 0; c4 < 16; ++c4) {
    float4 v = fT[c4];
    xs[(c4 * 4 + 0) * 256 + tid] = v.x;
    xs[(c4 * 4 + 1) * 256 + tid] = v.y;
    xs[(c4 * 4 + 2) * 256 + tid] = v.z;
    xs[(c4 * 4 + 3) * 256 + tid] = v.w;
  }

  const float* wt0 = wT;
  const float* wt1 = wT + 67 * 64;
  const float* wt2 = wT + 67 * 64 + 64 * 64;

  float acc[64];
  // ---------------- layer 0: 67 -> 64 ----------------
#pragma unroll
  for (int o = 0; o < 64; ++o) acc[o] = b0[o];
  {
    const float xr0 = x0, xr1 = x1, xr2 = x2;
    const float4* wr;
    wr = (const float4*)(wt0 + 0 * 64); MLP_FMA16(wr, xr0, acc);
    wr = (const float4*)(wt0 + 1 * 64); MLP_FMA16(wr, xr1, acc);
    wr = (const float4*)(wt0 + 2 * 64); MLP_FMA16(wr, xr2, acc);
  }
  for (int c = 0; c < 64; ++c) {
    float xc = xs[c * 256 + tid];
    const float4* wr = (const float4*)(wt0 + (3 + c) * 64);
    MLP_FMA16(wr, xc, acc);
  }
#pragma unroll
  for (int o = 0; o < 64; ++o) xs[o * 256 + tid] = fmaxf(acc[o], 0.0f);

  // ---------------- layer 1: 64 -> 64 ----------------
#pragma unroll
  for (int o = 0; o < 64; ++o) acc[o] = b1[o];
  for (int c = 0; c < 64; ++c) {
    float xc = xs[c * 256 + tid];
    const float4* wr = (const float4*)(wt1 + c * 64);
    MLP_FMA16(wr, xc, acc);
  }
#pragma unroll
  for (int o = 0; o < 64; ++o) xs[o * 256 + tid] = fmaxf(acc[o], 0.0f);

  // ---------------- layer 2: 64 -> 128 (two halves) + max over k ----------
#pragma unroll
  for (int h = 0; h < 2; ++h) {
#pragma unroll
    for (int o = 0; o < 64; ++o) acc[o] = b2[h * 64 + o];
    for (int c = 0; c < 64; ++c) {
      float xc = xs[c * 256 + tid];
      const float4* wr = (const float4*)(wt2 + c * 128 + h * 64);
      MLP_FMA16(wr, xc, acc);
    }
#pragma unroll
    for (int o = 0; o < 64; ++o) {
      float v = fmaxf(acc[o], 0.0f);
      v = fmaxf(v, __shfl_xor(v, 16, 64));
      v = fmaxf(v, __shfl_xor(v, 8, 64));
      v = fmaxf(v, __shfl_xor(v, 4, 64));
      v = fmaxf(v, __shfl_xor(v, 2, 64));
      v = fmaxf(v, __shfl_xor(v, 1, 64));
      if ((tid & 31) == 0)
        outf[((size_t)b * 128 + h * 64 + o) * NS + s] = v;
    }
  }
}

// ---------------------------------------------------------------------------
extern "C" void kernel_launch(void* const* d_in, const int* in_sizes, int n_in,
                              void* d_out, int out_size, void* d_ws,
                              size_t ws_size, hipStream_t stream) {
  const float* pos = (const float*)d_in[0];
  const float* feat = (const float*)d_in[1];
  const float* w0 = (const float*)d_in[2];
  const float* b0 = (const float*)d_in[3];
  const float* w1 = (const float*)d_in[4];
  const float* b1 = (const float*)d_in[5];
  const float* w2 = (const float*)d_in[6];
  const float* b2 = (const float*)d_in[7];

  float* out = (float*)d_out;
  float* new_xyz = out;                         // (B, S, 3)
  float* new_feat = out + (size_t)NB * NS * 3;  // (B, 128, S)

  int* ballidx = (int*)d_ws;                                    // B*S*K ints
  float* featT = (float*)d_ws + (size_t)NB * NS * NK;           // B*N*64
  float* wT = featT + (size_t)NB * NPTS * 64;                   // 16576 floats

  // transpose (featT, wT) -- tiny, independent of FPS
  hipLaunchKernelGGL(k_tp, dim3(NB * (NPTS / 64) + 1), dim3(256), 0, stream,
                     feat, w0, w1, w2, featT, wT);
  // FPS: one 512-thread block per batch (morton sort + pruned updates)
  hipLaunchKernelGGL(k_fps, dim3(NB), dim3(512), 0, stream, pos, new_xyz);
  // ball query: one wave per (b,s)
  hipLaunchKernelGGL(k_ball, dim3((NB * NS) / 4), dim3(256), 0, stream, pos,
                     new_xyz, ballidx);
  // gather + MLP + max-k
  hipLaunchKernelGGL(k_mlp, dim3((NB * NS * NK) / 256), dim3(256), 0, stream,
                     pos, featT, wT, b0, b1, b2, ballidx, new_xyz, new_feat);
}

// Round 8
// 2524.304 us; speedup vs baseline: 1.3090x; 1.3090x over previous
//
#include <hip/hip_runtime.h>

#define NB 8
#define NPTS 8192
#define NC_FEAT 64
#define NS 2048
#define NK 32

typedef float v2f __attribute__((ext_vector_type(2)));

// Exact reference arithmetic for squared distance: no fma contraction,
// sum association ((dx^2 + dy^2) + dz^2) to match XLA's linear reduce.
__device__ __forceinline__ float d2_ref(float px, float py, float pz,
                                        float qx, float qy, float qz) {
  float dx = __fsub_rn(px, qx);
  float dy = __fsub_rn(py, qy);
  float dz = __fsub_rn(pz, qz);
  return __fadd_rn(__fadd_rn(__fmul_rn(dx, dx), __fmul_rn(dy, dy)),
                   __fmul_rn(dz, dz));
}

// DPP max-combine on packed u64 key. bound_ctrl=true -> OOB lanes give 0.
#define DPP_KEYMAX(key, ctrl)                                                 \
  {                                                                           \
    unsigned _lo = (unsigned)__builtin_amdgcn_update_dpp(                     \
        0, (int)(unsigned)(key), (ctrl), 0xf, 0xf, true);                     \
    unsigned _hi = (unsigned)__builtin_amdgcn_update_dpp(                     \
        0, (int)(unsigned)((key) >> 32), (ctrl), 0xf, 0xf, true);             \
    unsigned long long _o = ((unsigned long long)_hi << 32) | _lo;            \
    if (_o > (key)) (key) = _o;                                               \
  }

// ---------------------------------------------------------------------------
// Kernel 0: FPS. One 256-thread block per batch (1 wave/SIMD -> per-wave
// fixed overhead paid once), 32 contiguous points per lane. Distance update
// in explicit v_pk_add/mul_f32 inline asm (guaranteed packed dual-FP32).
// px - qx emitted as px + (-qx): bit-identical. Argmax: ascending strict->
// scan keeps lowest local j = lowest original index (contiguous ownership);
// cross-lane via u64 (dist | ~idx) DPP max = exact jnp.argmax semantics.
// ---------------------------------------------------------------------------
__global__ __launch_bounds__(256)
void k_fps(const float* __restrict__ pos, float* __restrict__ new_xyz) {
#pragma clang fp contract(off)
  __shared__ __align__(16) float smem[3 * NPTS + 16];
  float* sx = smem;
  float* sy = smem + NPTS;
  float* sz = smem + 2 * NPTS;
  unsigned long long* rk = (unsigned long long*)(smem + 3 * NPTS);  // [2][4]

  const int tid = threadIdx.x;
  const int b = blockIdx.x;
  const float* p = pos + (size_t)b * NPTS * 3;

  for (int i = tid; i < NPTS; i += 256) {
    sx[i] = p[3 * i + 0];
    sy[i] = p[3 * i + 1];
    sz[i] = p[3 * i + 2];
  }
  if (tid < 8) rk[tid] = 0ull;
  __syncthreads();

  const int base = tid * 32;
  v2f px[16], py[16], pz[16], di[16];
#pragma unroll
  for (int k = 0; k < 16; ++k) {
    px[k] = *(const v2f*)&sx[base + 2 * k];
    py[k] = *(const v2f*)&sy[base + 2 * k];
    pz[k] = *(const v2f*)&sz[base + 2 * k];
    di[k] = (v2f){1e10f, 1e10f};
  }
  if (tid == 0) {
    new_xyz[((size_t)b * NS) * 3 + 0] = sx[0];
    new_xyz[((size_t)b * NS) * 3 + 1] = sy[0];
    new_xyz[((size_t)b * NS) * 3 + 2] = sz[0];
  }

  const int lane = tid & 63;
  const int wave = tid >> 6;
  int last = 0, buf = 0;

  for (int it = 1; it < NS; ++it) {
    float qx = sx[last], qy = sy[last], qz = sz[last];
    v2f nqx = (v2f){-qx, -qx};
    v2f nqy = (v2f){-qy, -qy};
    v2f nqz = (v2f){-qz, -qz};
    float bd = -1.0f;
    int bj = 0;
#pragma unroll
    for (int k = 0; k < 16; ++k) {
      v2f t0, t1, t2, d2v;
      // dx=px+(-qx); dy,dz likewise; d2=((dx*dx+dy*dy)+dz*dz), all packed.
      asm("v_pk_add_f32 %0, %4, %7\n\t"
          "v_pk_add_f32 %1, %5, %8\n\t"
          "v_pk_add_f32 %2, %6, %9\n\t"
          "v_pk_mul_f32 %0, %0, %0\n\t"
          "v_pk_mul_f32 %1, %1, %1\n\t"
          "v_pk_mul_f32 %2, %2, %2\n\t"
          "v_pk_add_f32 %3, %0, %1\n\t"
          "v_pk_add_f32 %3, %3, %2"
          : "=&v"(t0), "=&v"(t1), "=&v"(t2), "=&v"(d2v)
          : "v"(px[k]), "v"(py[k]), "v"(pz[k]), "v"(nqx), "v"(nqy), "v"(nqz));
      di[k] = __builtin_elementwise_min(di[k], d2v);
      if (di[k].x > bd) { bd = di[k].x; bj = 2 * k; }      // strict >:
      if (di[k].y > bd) { bd = di[k].y; bj = 2 * k + 1; }  // first max wins
    }
    unsigned long long key =
        ((unsigned long long)__float_as_uint(bd) << 32) |
        (unsigned)~(unsigned)(base + bj);
    // wave-level max via DPP: row_shr 1/2/4/8, bcast15, bcast31 -> lane63
    DPP_KEYMAX(key, 0x111);
    DPP_KEYMAX(key, 0x112);
    DPP_KEYMAX(key, 0x114);
    DPP_KEYMAX(key, 0x118);
    DPP_KEYMAX(key, 0x142);
    DPP_KEYMAX(key, 0x143);
    if (lane == 63) rk[buf * 4 + wave] = key;
    __syncthreads();
    // cross-wave: 4 partials; 2 DPP steps reduce into lane 3 of each group
    key = rk[buf * 4 + (lane & 3)];
    DPP_KEYMAX(key, 0x111);
    DPP_KEYMAX(key, 0x112);
    int fi = (int)~(unsigned)__builtin_amdgcn_readlane((int)(unsigned)key, 3);
    last = fi;
    buf ^= 1;
    if (tid == 0) {
      new_xyz[((size_t)b * NS + it) * 3 + 0] = sx[fi];
      new_xyz[((size_t)b * NS + it) * 3 + 1] = sy[fi];
      new_xyz[((size_t)b * NS + it) * 3 + 2] = sz[fi];
    }
  }
}

// ---------------------------------------------------------------------------
// Kernel 1: blocks 0..1023 = feature transpose (B,C,N)->(B,N,C) 64x64 tiles;
//           block 1024    = weight transpose to [c][o] layout.
// ---------------------------------------------------------------------------
__global__ __launch_bounds__(256)
void k_tp(const float* __restrict__ feat, const float* __restrict__ w0,
          const float* __restrict__ w1, const float* __restrict__ w2,
          float* __restrict__ featT, float* __restrict__ wT) {
  __shared__ float tile[64 * 65];
  const int tid = threadIdx.x;
  if (blockIdx.x < NB * (NPTS / 64)) {
    const int t = blockIdx.x;
    const int b = t >> 7;           // t / 128
    const int n0 = (t & 127) << 6;  // *64
    const int col = tid & 63;
    const int r0 = tid >> 6;  // 0..3
#pragma unroll
    for (int q = 0; q < 16; ++q) {
      int c = r0 + q * 4;
      tile[c * 65 + col] = feat[((size_t)b * NC_FEAT + c) * NPTS + n0 + col];
    }
    __syncthreads();
#pragma unroll
    for (int q = 0; q < 16; ++q) {
      int r = r0 + q * 4;
      featT[((size_t)b * NPTS + n0 + r) * 64 + col] = tile[col * 65 + r];
    }
  } else {
    for (int i = tid; i < 67 * 64; i += 256)
      wT[i] = w0[(i & 63) * 67 + (i >> 6)];
    for (int i = tid; i < 64 * 64; i += 256)
      wT[67 * 64 + i] = w1[(i & 63) * 64 + (i >> 6)];
    for (int i = tid; i < 64 * 128; i += 256)
      wT[67 * 64 + 64 * 64 + i] = w2[(i & 127) * 64 + (i >> 7)];
  }
}

// ---------------------------------------------------------------------------
// Kernel 2: ball query. One wave per query point; first-32-hits via ballot.
// ---------------------------------------------------------------------------
__global__ __launch_bounds__(256)
void k_ball(const float* __restrict__ pos, const float* __restrict__ nxyz,
            int* __restrict__ ballidx) {
  const int wid = (blockIdx.x * 256 + threadIdx.x) >> 6;  // global wave id
  const int lane = threadIdx.x & 63;
  const int b = wid >> 11;
  const float qx = nxyz[wid * 3 + 0];
  const float qy = nxyz[wid * 3 + 1];
  const float qz = nxyz[wid * 3 + 2];
  const float* p = pos + (size_t)b * NPTS * 3;
  int* outp = ballidx + (size_t)wid * NK;

  int cnt = 0;
  int firstidx = 0x7fffffff;
  for (int n0 = 0; n0 < NPTS; n0 += 64) {
    const int i = n0 + lane;
    float d2 = d2_ref(p[3 * i], p[3 * i + 1], p[3 * i + 2], qx, qy, qz);
    bool hit = d2 < 0.25f;
    unsigned long long mask = __ballot(hit);
    int pre = __popcll(mask & ((1ull << lane) - 1ull));
    int slot = cnt + pre;
    if (hit && slot < NK) outp[slot] = i;
    if (hit && slot == 0) firstidx = i;
    cnt += __popcll(mask);
    if (cnt >= NK) break;
  }
#pragma unroll
  for (int m = 32; m >= 1; m >>= 1)
    firstidx = min(firstidx, __shfl_xor(firstidx, m, 64));
  int pad = (firstidx == 0x7fffffff) ? 0 : firstidx;
  int start = cnt < NK ? cnt : NK;
  if (lane < NK && lane >= start) outp[lane] = pad;
}

// ---------------------------------------------------------------------------
// Kernel 3: gather + 3-layer MLP + max over k. One thread per (b,s,k) sample.
// Per-thread column in LDS (stride 256 -> conflict-free), weights read as
// wave-uniform float4 broadcasts from pre-transposed wT.
// ---------------------------------------------------------------------------
#define MLP_FMA16(wr, xc, acc)                                   \
  _Pragma("unroll") for (int o4 = 0; o4 < 16; ++o4) {            \
    float4 w = (wr)[o4];                                         \
    (acc)[o4 * 4 + 0] = fmaf(w.x, (xc), (acc)[o4 * 4 + 0]);      \
    (acc)[o4 * 4 + 1] = fmaf(w.y, (xc), (acc)[o4 * 4 + 1]);      \
    (acc)[o4 * 4 + 2] = fmaf(w.z, (xc), (acc)[o4 * 4 + 2]);      \
    (acc)[o4 * 4 + 3] = fmaf(w.w, (xc), (acc)[o4 * 4 + 3]);      \
  }

__global__ __launch_bounds__(256)
void k_mlp(const float* __restrict__ pos, const float* __restrict__ featT,
           const float* __restrict__ wT, const float* __restrict__ b0,
           const float* __restrict__ b1, const float* __restrict__ b2,
           const int* __restrict__ ballidx, const float* __restrict__ nxyz,
           float* __restrict__ outf) {
  __shared__ float xs[64 * 256];  // 64 KB: per-thread column, stride 256
  const int tid = threadIdx.x;
  const int g = blockIdx.x * 256 + tid;
  const int s = (g >> 5) & (NS - 1);
  const int b = g >> 16;

  const int idx = ballidx[g];
  const float qx = nxyz[((size_t)b * NS + s) * 3 + 0];
  const float qy = nxyz[((size_t)b * NS + s) * 3 + 1];
  const float qz = nxyz[((size_t)b * NS + s) * 3 + 2];
  const float* pp = pos + ((size_t)b * NPTS + idx) * 3;
  const float x0 = __fsub_rn(pp[0], qx);
  const float x1 = __fsub_rn(pp[1], qy);
  const float x2 = __fsub_rn(pp[2], qz);

  const float4* fT = (const float4*)(featT + ((size_t)b * NPTS + idx) * 64);
#pragma unroll
  for (int c4 = 0; c4 < 16; ++c4) {
    float4 v = fT[c4];
    xs[(c4 * 4 + 0) * 256 + tid] = v.x;
    xs[(c4 * 4 + 1) * 256 + tid] = v.y;
    xs[(c4 * 4 + 2) * 256 + tid] = v.z;
    xs[(c4 * 4 + 3) * 256 + tid] = v.w;
  }

  const float* wt0 = wT;
  const float* wt1 = wT + 67 * 64;
  const float* wt2 = wT + 67 * 64 + 64 * 64;

  float acc[64];
  // ---------------- layer 0: 67 -> 64 ----------------
#pragma unroll
  for (int o = 0; o < 64; ++o) acc[o] = b0[o];
  {
    const float xr0 = x0, xr1 = x1, xr2 = x2;
    const float4* wr;
    wr = (const float4*)(wt0 + 0 * 64); MLP_FMA16(wr, xr0, acc);
    wr = (const float4*)(wt0 + 1 * 64); MLP_FMA16(wr, xr1, acc);
    wr = (const float4*)(wt0 + 2 * 64); MLP_FMA16(wr, xr2, acc);
  }
  for (int c = 0; c < 64; ++c) {
    float xc = xs[c * 256 + tid];
    const float4* wr = (const float4*)(wt0 + (3 + c) * 64);
    MLP_FMA16(wr, xc, acc);
  }
#pragma unroll
  for (int o = 0; o < 64; ++o) xs[o * 256 + tid] = fmaxf(acc[o], 0.0f);

  // ---------------- layer 1: 64 -> 64 ----------------
#pragma unroll
  for (int o = 0; o < 64; ++o) acc[o] = b1[o];
  for (int c = 0; c < 64; ++c) {
    float xc = xs[c * 256 + tid];
    const float4* wr = (const float4*)(wt1 + c * 64);
    MLP_FMA16(wr, xc, acc);
  }
#pragma unroll
  for (int o = 0; o < 64; ++o) xs[o * 256 + tid] = fmaxf(acc[o], 0.0f);

  // ---------------- layer 2: 64 -> 128 (two halves) + max over k ----------
#pragma unroll
  for (int h = 0; h < 2; ++h) {
#pragma unroll
    for (int o = 0; o < 64; ++o) acc[o] = b2[h * 64 + o];
    for (int c = 0; c < 64; ++c) {
      float xc = xs[c * 256 + tid];
      const float4* wr = (const float4*)(wt2 + c * 128 + h * 64);
      MLP_FMA16(wr, xc, acc);
    }
#pragma unroll
    for (int o = 0; o < 64; ++o) {
      float v = fmaxf(acc[o], 0.0f);
      v = fmaxf(v, __shfl_xor(v, 16, 64));
      v = fmaxf(v, __shfl_xor(v, 8, 64));
      v = fmaxf(v, __shfl_xor(v, 4, 64));
      v = fmaxf(v, __shfl_xor(v, 2, 64));
      v = fmaxf(v, __shfl_xor(v, 1, 64));
      if ((tid & 31) == 0)
        outf[((size_t)b * 128 + h * 64 + o) * NS + s] = v;
    }
  }
}

// ---------------------------------------------------------------------------
extern "C" void kernel_launch(void* const* d_in, const int* in_sizes, int n_in,
                              void* d_out, int out_size, void* d_ws,
                              size_t ws_size, hipStream_t stream) {
  const float* pos = (const float*)d_in[0];
  const float* feat = (const float*)d_in[1];
  const float* w0 = (const float*)d_in[2];
  const float* b0 = (const float*)d_in[3];
  const float* w1 = (const float*)d_in[4];
  const float* b1 = (const float*)d_in[5];
  const float* w2 = (const float*)d_in[6];
  const float* b2 = (const float*)d_in[7];

  float* out = (float*)d_out;
  float* new_xyz = out;                         // (B, S, 3)
  float* new_feat = out + (size_t)NB * NS * 3;  // (B, 128, S)

  int* ballidx = (int*)d_ws;                                    // B*S*K ints
  float* featT = (float*)d_ws + (size_t)NB * NS * NK;           // B*N*64
  float* wT = featT + (size_t)NB * NPTS * 64;                   // 16576 floats

  // transpose (featT, wT) -- tiny, independent of FPS
  hipLaunchKernelGGL(k_tp, dim3(NB * (NPTS / 64) + 1), dim3(256), 0, stream,
                     feat, w0, w1, w2, featT, wT);
  // FPS: one 256-thread block per batch, packed-f32 asm inner loop
  hipLaunchKernelGGL(k_fps, dim3(NB), dim3(256), 0, stream, pos, new_xyz);
  // ball query: one wave per (b,s)
  hipLaunchKernelGGL(k_ball, dim3((NB * NS) / 4), dim3(256), 0, stream, pos,
                     new_xyz, ballidx);
  // gather + MLP + max-k
  hipLaunchKernelGGL(k_mlp, dim3((NB * NS * NK) / 256), dim3(256), 0, stream,
                     pos, featT, wT, b0, b1, b2, ballidx, new_xyz, new_feat);
}